// Round 5
// baseline (345.666 us; speedup 1.0000x reference)
//
#include <hip/hip_runtime.h>
#include <hip/hip_bf16.h>

typedef unsigned short u16;
typedef unsigned int   u32;
typedef __attribute__((ext_vector_type(8))) short bf16x8;
typedef __attribute__((ext_vector_type(4))) float f32x4;
typedef __attribute__((ext_vector_type(4))) u32   u32x4;

#define GENES  12132
#define KPAD   12160        // 190 * 64, zero-padded W tail
#define NROW   16384
#define GCOL   64
#define KTAIL  12096        // 378 * 32; xpad covers k in [KTAIL, KPAD)
#define CHUNKS32 380        // KPAD / 32
#define KSPLIT 5
#define CPW    76           // chunks (K=32) per split

// ---- fp32 -> bf16 hi/lo split helpers (v_perm packs 2 elts/inst) -----------
__device__ __forceinline__ u32 pack_hi(float x, float y) {
  return __builtin_amdgcn_perm(__float_as_uint(y), __float_as_uint(x), 0x07060302u);
}
__device__ __forceinline__ u32 pack_lo(float x, float y) {
  float lx = x - __uint_as_float(__float_as_uint(x) & 0xFFFF0000u);
  float ly = y - __uint_as_float(__float_as_uint(y) & 0xFFFF0000u);
  return pack_hi(lx, ly);
}
__device__ __forceinline__ void cvt8(const float* __restrict__ p, bf16x8& h8, bf16x8& l8) {
  const f32x4 a = *(const f32x4*)p;
  const f32x4 b = *(const f32x4*)(p + 4);
  u32x4 hv = { pack_hi(a[0], a[1]), pack_hi(a[2], a[3]),
               pack_hi(b[0], b[1]), pack_hi(b[2], b[3]) };
  u32x4 lv = { pack_lo(a[0], a[1]), pack_lo(a[2], a[3]),
               pack_lo(b[0], b[1]), pack_lo(b[2], b[3]) };
  h8 = __builtin_bit_cast(bf16x8, hv);
  l8 = __builtin_bit_cast(bf16x8, lv);
}

// ---------------- fused prep: W split/transpose + xpad + zero inits ---------
__global__ __launch_bounds__(256) void prep_all(
    const float* __restrict__ gw, const float* __restrict__ ns,
    const float* __restrict__ x,
    u16* __restrict__ Wth, u16* __restrict__ Wtl,
    float* __restrict__ xpad, float* __restrict__ hbuf) {
  const int bid = blockIdx.x;
  const int t   = threadIdx.x;
  if (bid < KPAD / 64) {
    __shared__ u16 th[64 * 72];
    __shared__ u16 tl[64 * 72];
    const int k0 = bid * 64;
#pragma unroll
    for (int i = 0; i < 16; ++i) {
      int idx = i * 256 + t;
      int k = idx >> 6, c = idx & 63;
      int gk = k0 + k;
      float wv = 0.f;
      if (gk < GENES) wv = gw[(size_t)gk * GCOL + c] / ns[gk];
      u32 u = __float_as_uint(wv);
      float lf = wv - __uint_as_float(u & 0xFFFF0000u);
      th[c * 72 + k] = (u16)(u >> 16);
      tl[c * 72 + k] = (u16)(__float_as_uint(lf) >> 16);
    }
    __syncthreads();
    const int c  = t >> 2;
    const int kk = (t & 3) * 16;
    uint4 a0 = *(const uint4*)(th + c * 72 + kk);
    uint4 a1 = *(const uint4*)(th + c * 72 + kk + 8);
    uint4 b0 = *(const uint4*)(tl + c * 72 + kk);
    uint4 b1 = *(const uint4*)(tl + c * 72 + kk + 8);
    *(uint4*)(Wth + (size_t)c * KPAD + k0 + kk)     = a0;
    *(uint4*)(Wth + (size_t)c * KPAD + k0 + kk + 8) = a1;
    *(uint4*)(Wtl + (size_t)c * KPAD + k0 + kk)     = b0;
    *(uint4*)(Wtl + (size_t)c * KPAD + k0 + kk + 8) = b1;
  } else {
    int i = (bid - KPAD / 64) * 256 + t;   // over NROW*64
    int row = i >> 6, col = i & 63;
    float v = 0.f;
    if (col < GENES - KTAIL) v = x[(size_t)row * GENES + KTAIL + col];
    xpad[i] = v;
    if (bid == KPAD / 64 && t < 64) hbuf[t] = 0.f;
  }
}

// ---------------- GEMM: xwp[sp][N,64] partial of x @ W' (split-bf16 MFMA) ---
// 1280 blocks x 64 threads (1 wave). Wave owns 64 rows x 64 cols x K/5.
// No LDS, no barriers: A fragments stream global->VGPR (16 rows x 128 B
// contiguous per row), B fragments from L2-resident transposed W planes.
__global__ __launch_bounds__(64) void gemm_kernel(
    const float* __restrict__ x, const float* __restrict__ xpad,
    const u16* __restrict__ Wth, const u16* __restrict__ Wtl,
    float* __restrict__ xwp) {
  const int wid = blockIdx.x;      // 0..1279
  const int sp  = wid >> 8;        // 0..4 (k-split)
  const int rg  = wid & 255;       // row-group: 64 rows
  const int l   = threadIdx.x;
  const int lr  = l & 15;
  const int kq  = l >> 4;          // 0..3

  const int r0 = rg * 64;

  f32x4 acc[4][4];
#pragma unroll
  for (int s = 0; s < 4; ++s)
#pragma unroll
    for (int c = 0; c < 4; ++c) acc[s][c] = (f32x4){0.f, 0.f, 0.f, 0.f};

  const u16* bh_base = Wth + (size_t)lr * KPAD + kq * 8;
  const u16* bl_base = Wtl + (size_t)lr * KPAD + kq * 8;
  const int gch0 = sp * CPW;

#pragma unroll 2
  for (int ci = 0; ci < CPW; ++ci) {
    const int gch = gch0 + ci;
    const int k0  = gch * 32;
    // B fragment loads (16 B each, L2-resident)
    bf16x8 bh[4], bl[4];
#pragma unroll
    for (int cg = 0; cg < 4; ++cg) {
      bh[cg] = *(const bf16x8*)(bh_base + (size_t)cg * (16 * KPAD) + k0);
      bl[cg] = *(const bf16x8*)(bl_base + (size_t)cg * (16 * KPAD) + k0);
    }
    // A fragment loads (32 B/lane) + in-register split to bf16 hi/lo
    bf16x8 ah[4], al[4];
    if (gch < KTAIL / 32) {
#pragma unroll
      for (int s = 0; s < 4; ++s)
        cvt8(x + (size_t)(r0 + s * 16 + lr) * GENES + k0 + kq * 8, ah[s], al[s]);
    } else {
#pragma unroll
      for (int s = 0; s < 4; ++s)
        cvt8(xpad + (size_t)(r0 + s * 16 + lr) * 64 + (k0 - KTAIL) + kq * 8, ah[s], al[s]);
    }
    // acc += ah*bh + al*bh + ah*bl  (split-bf16 ~= fp32)
#pragma unroll
    for (int s = 0; s < 4; ++s)
#pragma unroll
      for (int cg = 0; cg < 4; ++cg) {
        acc[s][cg] = __builtin_amdgcn_mfma_f32_16x16x32_bf16(ah[s], bh[cg], acc[s][cg], 0, 0, 0);
        acc[s][cg] = __builtin_amdgcn_mfma_f32_16x16x32_bf16(al[s], bh[cg], acc[s][cg], 0, 0, 0);
        acc[s][cg] = __builtin_amdgcn_mfma_f32_16x16x32_bf16(ah[s], bl[cg], acc[s][cg], 0, 0, 0);
      }
  }

  // store partials; C/D layout: col=lane&15, row=(lane>>4)*4+reg
  float* outp = xwp + (size_t)sp * NROW * GCOL;
#pragma unroll
  for (int s = 0; s < 4; ++s) {
    const int rbase = r0 + s * 16 + kq * 4;
#pragma unroll
    for (int cg = 0; cg < 4; ++cg) {
      const int col = cg * 16 + lr;
#pragma unroll
      for (int j = 0; j < 4; ++j)
        outp[(size_t)(rbase + j) * GCOL + col] = acc[s][cg][j];
    }
  }
}

// ---------------- reduce planes -> xw; fused sel extraction -----------------
__global__ __launch_bounds__(256) void reduce_sel(
    const f32x4* __restrict__ xwp, f32x4* __restrict__ xw4,
    const float* __restrict__ gb, float* __restrict__ sel) {
  int i = blockIdx.x * 256 + threadIdx.x;   // over NROW*GCOL/4 = 262144
  f32x4 v = xwp[i];
#pragma unroll
  for (int p = 1; p < KSPLIT; ++p) {
    f32x4 u = xwp[(size_t)p * (NROW * GCOL / 4) + i];
    v[0] += u[0]; v[1] += u[1]; v[2] += u[2]; v[3] += u[3];
  }
  xw4[i] = v;
  int row = i >> 4;
  int g = row >> 8;                         // graph_ids[i] == i>>8 structurally
  if ((i & 15) == (g >> 2)) sel[row] = v[g & 3] + gb[g];
}

// ---------------- edge scatter: sel[dst] += xw[src, g_dst] ------------------
__global__ __launch_bounds__(256) void edge_kernel(
    const int* __restrict__ ei, const float* __restrict__ xw,
    float* __restrict__ sel, int E) {
  int e = blockIdx.x * 256 + threadIdx.x;
  if (e < E) {
    int s = ei[e];
    int d = ei[E + e];
    int g = d >> 8;
    atomicAdd(&sel[d], xw[(size_t)s * GCOL + g]);
  }
}

// ---------------- hbuf[k] += partial( w1[k,:] . sel ) -----------------------
__global__ __launch_bounds__(256) void hreduce_kernel(
    const float* __restrict__ w1, const float* __restrict__ sel,
    float* __restrict__ hbuf) {
  const int k = blockIdx.x >> 2;
  const int q = blockIdx.x & 3;
  const int t = threadIdx.x;
  const float4* wr = reinterpret_cast<const float4*>(w1 + (size_t)k * NROW);
  const float4* sv = reinterpret_cast<const float4*>(sel);
  float sum = 0.f;
#pragma unroll
  for (int i = 0; i < 4; ++i) {
    int idx = q * 1024 + i * 256 + t;
    float4 a = wr[idx];
    float4 b = sv[idx];
    sum += a.x * b.x + a.y * b.y + a.z * b.z + a.w * b.w;
  }
#pragma unroll
  for (int off = 32; off > 0; off >>= 1) sum += __shfl_down(sum, off, 64);
  __shared__ float wsum[4];
  if ((t & 63) == 0) wsum[t >> 6] = sum;
  __syncthreads();
  if (t == 0) atomicAdd(&hbuf[k], wsum[0] + wsum[1] + wsum[2] + wsum[3]);
}

// ---------------- finalize: h->normalize->w2 dot->sigmoid (one wave) --------
__global__ void finalize_kernel(
    const float* __restrict__ hbuf, const float* __restrict__ b1,
    const float* __restrict__ fm, const float* __restrict__ fs,
    const float* __restrict__ w2, const float* __restrict__ b2,
    float* __restrict__ out) {
  int t = threadIdx.x;    // 64 threads
  float h  = hbuf[t] + b1[t];
  float hn = (h - fm[t]) / fs[t];
  float v  = w2[t] * hn;
#pragma unroll
  for (int off = 32; off > 0; off >>= 1) v += __shfl_down(v, off, 64);
  if (t == 0) {
    float z = v + b2[0];
    out[0] = 1.f / (1.f + expf(-z));
  }
}

extern "C" void kernel_launch(void* const* d_in, const int* in_sizes, int n_in,
                              void* d_out, int out_size, void* d_ws, size_t ws_size,
                              hipStream_t stream) {
  const float* x    = (const float*)d_in[0];
  const int*   ei   = (const int*)d_in[1];
  const float* ns   = (const float*)d_in[3];
  const float* gw   = (const float*)d_in[4];
  const float* gb   = (const float*)d_in[5];
  const float* w1   = (const float*)d_in[6];
  const float* b1   = (const float*)d_in[7];
  const float* fm   = (const float*)d_in[8];
  const float* fs   = (const float*)d_in[9];
  const float* w2   = (const float*)d_in[10];
  const float* b2   = (const float*)d_in[11];
  float* out = (float*)d_out;

  const int E = in_sizes[1] / 2;

  float* ws   = (float*)d_ws;
  float* xw   = ws;                                  // 1,048,576 f32
  float* sel  = xw + (size_t)NROW * GCOL;            // 16,384 f32
  float* hbuf = sel + NROW;                          // 64 f32
  u16*   Wth  = (u16*)(hbuf + 64);                   // 64*KPAD u16
  u16*   Wtl  = Wth + (size_t)GCOL * KPAD;
  float* xpad = (float*)(Wtl + (size_t)GCOL * KPAD); // NROW*64 f32
  float* xwp  = xpad + (size_t)NROW * 64;            // KSPLIT*NROW*64 f32

  hipLaunchKernelGGL(prep_all, dim3(KPAD / 64 + NROW * 64 / 256), dim3(256), 0, stream,
                     gw, ns, x, Wth, Wtl, xpad, hbuf);
  hipLaunchKernelGGL(gemm_kernel, dim3(256 * KSPLIT), dim3(64), 0, stream,
                     x, xpad, Wth, Wtl, xwp);
  hipLaunchKernelGGL(reduce_sel, dim3(NROW * GCOL / 4 / 256), dim3(256), 0, stream,
                     (const f32x4*)xwp, (f32x4*)xw, gb, sel);
  hipLaunchKernelGGL(edge_kernel, dim3((E + 255) / 256), dim3(256), 0, stream,
                     ei, xw, sel, E);
  hipLaunchKernelGGL(hreduce_kernel, dim3(GCOL * 4), dim3(256), 0, stream,
                     w1, sel, hbuf);
  hipLaunchKernelGGL(finalize_kernel, dim3(1), dim3(64), 0, stream,
                     hbuf, b1, fm, fs, w2, b2, out);
}